// Round 1
// baseline (235.459 us; speedup 1.0000x reference)
//
#include <hip/hip_runtime.h>

constexpr int N_NODES = 100000;
constexpr int N_EDGES = 1000000;
constexpr int DIM = 64;

constexpr int SCAN_BLK = 512;
constexpr int NBLK = (N_NODES + SCAN_BLK - 1) / SCAN_BLK;   // 196

constexpr int TILE = 64;    // nodes per fused block
constexpr int PAD = 65;     // LDS row stride (floats) — breaks bank conflicts

// --- Phase 1: degree histogram, 4 edges per thread (int4 loads) -------------
__global__ __launch_bounds__(256) void count_deg(
    const int* __restrict__ eidx, int* __restrict__ deg)
{
    int t = blockIdx.x * 256 + threadIdx.x;
    if (t >= N_EDGES / 4) return;
    int4 v = reinterpret_cast<const int4*>(eidx)[t];
    atomicAdd(&deg[v.x], 1);
    atomicAdd(&deg[v.y], 1);
    atomicAdd(&deg[v.z], 1);
    atomicAdd(&deg[v.w], 1);
}

// --- Phase 2: exclusive prefix scan of deg -> offs --------------------------
__global__ __launch_bounds__(SCAN_BLK) void scan_block(
    const int* __restrict__ deg, int* __restrict__ offs, int* __restrict__ bsums)
{
    __shared__ int s[SCAN_BLK];
    int n = blockIdx.x * SCAN_BLK + threadIdx.x;
    int v = (n < N_NODES) ? deg[n] : 0;
    s[threadIdx.x] = v;
    __syncthreads();
    for (int d = 1; d < SCAN_BLK; d <<= 1) {
        int t = (threadIdx.x >= d) ? s[threadIdx.x - d] : 0;
        __syncthreads();
        s[threadIdx.x] += t;
        __syncthreads();
    }
    if (n < N_NODES) offs[n] = s[threadIdx.x] - v;          // exclusive within block
    if (threadIdx.x == SCAN_BLK - 1) bsums[blockIdx.x] = s[SCAN_BLK - 1];
}

__global__ __launch_bounds__(256) void scan_sums(int* __restrict__ bsums)
{
    __shared__ int s[256];
    int v = (threadIdx.x < NBLK) ? bsums[threadIdx.x] : 0;
    s[threadIdx.x] = v;
    __syncthreads();
    for (int d = 1; d < 256; d <<= 1) {
        int t = (threadIdx.x >= d) ? s[threadIdx.x - d] : 0;
        __syncthreads();
        s[threadIdx.x] += t;
        __syncthreads();
    }
    if (threadIdx.x < NBLK) bsums[threadIdx.x] = s[threadIdx.x] - v;  // exclusive
}

__global__ __launch_bounds__(SCAN_BLK) void add_base(
    int* __restrict__ offs, const int* __restrict__ bsums)
{
    int n = blockIdx.x * SCAN_BLK + threadIdx.x;
    if (blockIdx.x == 0 && threadIdx.x == 0)
        offs[N_NODES] = N_EDGES;                 // sentinel: deg = offs diff
    if (n >= N_NODES) return;
    offs[n] += bsums[blockIdx.x];
}

// --- Phase 3: scatter sources into CSR buckets (cursor atomic = ticket) -----
__global__ __launch_bounds__(256) void scatter_kernel(
    const int* __restrict__ eidx, const int* __restrict__ offs,
    int* __restrict__ cursor, int* __restrict__ bucket)
{
    int e = blockIdx.x * 256 + threadIdx.x;
    if (e >= N_EDGES) return;
    int i = eidx[e];
    int j = eidx[N_EDGES + e];
    int pos = atomicAdd(&cursor[i], 1);
    bucket[offs[i] + pos] = j;
}

// --- Phase 4 (fused): gather mean + 64x64 matmul + bias ---------------------
// Block = 256 threads = 4 waves, one 64-node tile.
//   Gather: wave w owns nodes wbase..wbase+15. Wave preloads its 17 CSR
//           offsets (one coalesced load), then per node the 4 16-lane groups
//           each read a DIFFERENT edge's x-row as float4 (16 lanes x 16B =
//           256B row). One load instruction = 4 rows in flight; unroll 2 = 8.
//           Cross-group reduce via __shfl_xor(16/32).
//   Matmul: thread t computes out[base + (t&63)][d0..d0+15], d0=(t>>6)*16.
__global__ __launch_bounds__(256) void fused_gather_mm(
    const float* __restrict__ x, const int* __restrict__ offs,
    const int* __restrict__ deg, const int* __restrict__ bucket,
    const float* __restrict__ W, const float* __restrict__ b,
    float* __restrict__ out)
{
    __shared__ float tile[TILE * PAD];   // 16.6 KB

    const int base = blockIdx.x * TILE;
    const int lane = threadIdx.x & 63;
    const int wid  = threadIdx.x >> 6;   // 0..3
    const int grp  = lane >> 4;          // 0..3: which edge within a 4-pack
    const int gl4  = (lane & 15) << 2;   // feature offset 0,4,..,60

    // ---- wave-cooperative preload of 17 CSR offsets ----
    const int wbase = base + wid * 16;
    int offs_pre = 0;
    if (lane < 17) {
        int nn = wbase + lane;
        offs_pre = offs[nn < N_NODES ? nn : N_NODES];
    }

    for (int i = 0; i < 16; ++i) {
        const int start = __builtin_amdgcn_readlane(offs_pre, i);
        const int dend  = __builtin_amdgcn_readlane(offs_pre, i + 1);
        const int d     = dend - start;

        float sx = 0.0f, sy = 0.0f, sz = 0.0f, sw = 0.0f;
        int e = 0;
        for (; e + 8 <= d; e += 8) {         // 8 rows in flight
            int j0 = bucket[start + e + grp];
            int j1 = bucket[start + e + 4 + grp];
            const float4 v0 = *reinterpret_cast<const float4*>(x + ((size_t)j0 << 6) + gl4);
            const float4 v1 = *reinterpret_cast<const float4*>(x + ((size_t)j1 << 6) + gl4);
            sx += v0.x + v1.x; sy += v0.y + v1.y;
            sz += v0.z + v1.z; sw += v0.w + v1.w;
        }
        if (e + 4 <= d) {                    // 4-row tail
            int j0 = bucket[start + e + grp];
            const float4 v0 = *reinterpret_cast<const float4*>(x + ((size_t)j0 << 6) + gl4);
            sx += v0.x; sy += v0.y; sz += v0.z; sw += v0.w;
            e += 4;
        }
        if (grp < d - e) {                   // 1..3-row tail
            int j0 = bucket[start + e + grp];
            const float4 v0 = *reinterpret_cast<const float4*>(x + ((size_t)j0 << 6) + gl4);
            sx += v0.x; sy += v0.y; sz += v0.z; sw += v0.w;
        }

        // ---- reduce the 4 groups: lane^16 then lane^32 ----
        sx += __shfl_xor(sx, 16); sy += __shfl_xor(sy, 16);
        sz += __shfl_xor(sz, 16); sw += __shfl_xor(sw, 16);
        sx += __shfl_xor(sx, 32); sy += __shfl_xor(sy, 32);
        sz += __shfl_xor(sz, 32); sw += __shfl_xor(sw, 32);

        if (grp == 0) {
            const float inv = (d > 0) ? 1.0f / (float)d : 0.0f;
            float* tr = &tile[(wid * 16 + i) * PAD + gl4];
            tr[0] = sx * inv; tr[1] = sy * inv;
            tr[2] = sz * inv; tr[3] = sw * inv;
        }
    }
    __syncthreads();

    // ---- matmul: acc[q] = sum_k agg[nd][k] * W[d0+q][k] ----
    const int nd  = threadIdx.x & 63;
    const int d0u = __builtin_amdgcn_readfirstlane((threadIdx.x >> 6) << 4);
    const float* __restrict__ Wr = W + (size_t)d0u * DIM;   // uniform base -> s_load

    float acc[16];
#pragma unroll
    for (int q = 0; q < 16; ++q) acc[q] = 0.0f;

#pragma unroll 4
    for (int k = 0; k < DIM; ++k) {
        float a = tile[nd * PAD + k];    // lane*65+k: conflict-free
#pragma unroll
        for (int q = 0; q < 16; ++q)
            acc[q] = fmaf(a, Wr[(size_t)q * DIM + k], acc[q]);
    }

    // ---- epilogue: mask + bias, round-trip LDS for coalesced store ----
    int gnode = base + nd;
    int dg = (gnode < N_NODES) ? deg[gnode] : 0;
    __syncthreads();                     // everyone done reading agg
#pragma unroll
    for (int q = 0; q < 16; ++q) {
        float v = (dg > 0) ? (acc[q] + b[d0u + q]) : 0.0f;
        tile[nd * PAD + d0u + q] = v;    // lane*65 + const: conflict-free
    }
    __syncthreads();

#pragma unroll
    for (int r = 0; r < 16; ++r) {
        int idx = r * 256 + threadIdx.x;           // 0..4095
        int row = idx >> 6, d = idx & 63;
        int g = base + row;
        if (g < N_NODES)
            out[(size_t)g * DIM + d] = tile[row * PAD + d];
    }
}

extern "C" void kernel_launch(void* const* d_in, const int* in_sizes, int n_in,
                              void* d_out, int out_size, void* d_ws, size_t ws_size,
                              hipStream_t stream) {
    const float* x  = (const float*)d_in[0];   // (N, 64)
    const int*   ei = (const int*)d_in[1];     // (2, E): [0,E) targets, [E,2E) sources
    const float* W  = (const float*)d_in[2];   // (64, 64)
    const float* b  = (const float*)d_in[3];   // (64,)
    float* out = (float*)d_out;                // (N, 64)

    // Workspace layout (~5.2 MB)
    int* deg    = (int*)d_ws;            // N
    int* cursor = deg + N_NODES;         // N   (zeroed together with deg)
    int* offs   = cursor + N_NODES;      // N+1 (sentinel offs[N] = E)
    int* bucket = offs + (N_NODES + 1);  // E
    int* bsums  = bucket + N_EDGES;      // 256

    // deg + cursor are adjacent: one memset covers both.
    hipMemsetAsync(deg, 0, 2 * N_NODES * sizeof(int), stream);

    count_deg<<<(N_EDGES / 4 + 255) / 256, 256, 0, stream>>>(ei, deg);
    scan_block<<<NBLK, SCAN_BLK, 0, stream>>>(deg, offs, bsums);
    scan_sums<<<1, 256, 0, stream>>>(bsums);
    add_base<<<NBLK, SCAN_BLK, 0, stream>>>(offs, bsums);
    scatter_kernel<<<(N_EDGES + 255) / 256, 256, 0, stream>>>(ei, offs, cursor, bucket);
    fused_gather_mm<<<(N_NODES + TILE - 1) / TILE, 256, 0, stream>>>(
        x, offs, deg, bucket, W, b, out);
}